// Round 6
// baseline (133.767 us; speedup 1.0000x reference)
//
#include <hip/hip_runtime.h>
#include <hip/hip_bf16.h>
#include <math.h>

constexpr int NCAPS = 1152;
constexpr int CIN   = 8;
constexpr int COUT  = 16;
constexpr int BATCH = 128;
constexpr int DCAPS = 10;

// R6: fused kernel, 2 b's per block, w staged via global_load_lds.
//
// R5 diagnosis: spill fixed (WRITE 86MB->80KB) but 64 us with HBM 5%,
// VALU 15%, occupancy 26% -> latency-bound on per-block w L2 streaming
// (854 MB chip-wide through per-XCD L2 ~ 24.6 us floor, x2.6 from poor MLP:
// 144 plain global loads/thread at ~250cy with 16 waves/CU).
//
// Fix (T3+T4 from the 8-phase template):
//  - 2 b's/block (512 thr, 640 blocks): w read once per block -> L2 traffic
//    754 -> 377 MB (~11 us floor).
//  - w staged in 32-KB stages (64 rows) via global_load_lds width=16,
//    double-buffered; counted s_waitcnt vmcnt(4) so the NEXT stage's DMA is
//    in flight across barriers while the current stage computes. Raw
//    s_barrier builtin (NOT __syncthreads -- that drains vmcnt(0)).
//  - LDS dest linear (DMA requirement); reads use XOR swizzle
//    byte ^= ((row&7)<<4); the DMA *source* address is pre-swizzled with the
//    same involution (rule: swizzle both sides via source, m173 pattern).
//  - phase-1 thread = (ih=i-half, oq=o-quad, row): 4x ds_read_b128 of w,
//    partner lanes (shfl_xor 1) hold the two i-halves; after cross-add both
//    lanes have full sums for both b's; lane ih writes b_ih's o-quad to u_lds.
//
// LDS: u 73728 (2 b x 2304 uint4) + w 2x32768 + red/zred/vsh = 139,936 B
// -> 1 block/CU, 8 waves. Latency hidden by DMA queue depth, not occupancy.
//
// Phase 2: identical routing math as R5, per-b: waves 0-3 -> b0, 4-7 -> b1.

constexpr int BNT   = 512;
constexpr int BWAV  = 8;
constexpr int JPT   = 9;              // phase-2 half-rows per thread (per b)
constexpr int NSTG  = 18;             // 18 stages x 64 n-rows
constexpr int STG_B = 32768;          // bytes of w per stage (64 rows x 512 B)

__device__ __forceinline__ void unpack8(const uint4 pv, float* f) {
    f[0] = __uint_as_float(pv.x << 16);
    f[1] = __uint_as_float(pv.x & 0xffff0000u);
    f[2] = __uint_as_float(pv.y << 16);
    f[3] = __uint_as_float(pv.y & 0xffff0000u);
    f[4] = __uint_as_float(pv.z << 16);
    f[5] = __uint_as_float(pv.z & 0xffff0000u);
    f[6] = __uint_as_float(pv.w << 16);
    f[7] = __uint_as_float(pv.w & 0xffff0000u);
}

__device__ __forceinline__ void dma16(const void* g, void* l) {
    __builtin_amdgcn_global_load_lds(
        (const __attribute__((address_space(1))) unsigned int*)g,
        (__attribute__((address_space(3))) unsigned int*)l,
        16, 0, 0);
}

__global__ __launch_bounds__(BNT) void fused_caps_kernel(
    const float* __restrict__ x,      // [128, 1152, 8]
    const float* __restrict__ w,      // [10, 1152, 8, 16]
    float* __restrict__ out)          // [10, 128, 16]
{
    __shared__ uint4 u_lds[2 * JPT * 256];            // 73728 B packed bf16 u
    __shared__ __align__(16) char w_lds[2][STG_B];    // 65536 B w stages
    __shared__ float red[BWAV][COUT];
    __shared__ float zred[BWAV];
    __shared__ float vsh[2][COUT];

    // ---- block -> (d, b-pair), XCD-grouped by d (bijective over 640) ----
    const int i = blockIdx.x;
    int d, bp;
    if (i < 512) { d = i & 7; bp = i >> 3; }
    else { const int j2 = i - 512; d = 8 + (j2 & 1); bp = j2 >> 1; }
    const int b0 = bp * 2;

    const int t    = threadIdx.x;
    const int wave = t >> 6;
    const int lane = t & 63;

    // phase-1 decode: t = row*8 + oq*2 + ih
    const int ih  = t & 1;            // i-half: 0 -> i 0..3, 1 -> i 4..7
    const int oq  = (t >> 1) & 3;     // o-quad
    const int row = t >> 3;           // 0..63 within stage

    const char*  wd  = (const char*)w + (size_t)d * (NCAPS * CIN * COUT) * 4;
    const float* xb0 = x + (size_t)b0 * (NCAPS * CIN);
    const float* xb1 = xb0 + (NCAPS * CIN);

    // stage SS (64 w-rows, 32 KB) into w_lds[SS&1]; 4 dma16 per thread.
    // LDS dest linear; global source pre-swizzled with the read-side
    // involution  L ^= ((L>>9)&7)<<4  (XOR bits 4-6 with row bits 0-2).
    auto STAGE = [&](int ss) {
        const int buf = ss & 1;
        const size_t gbase = (size_t)ss * STG_B;
        #pragma unroll
        for (int it = 0; it < 4; ++it) {
            const int L = it * 8192 + wave * 1024 + lane * 16;
            const int g = L ^ (((L >> 9) & 7) << 4);
            dma16(wd + gbase + (size_t)g, &w_lds[buf][it * 8192 + wave * 1024]);
        }
    };

    STAGE(0);

    for (int s = 0; s < NSTG; ++s) {
        if (s < NSTG - 1) {
            STAGE(s + 1);
            asm volatile("s_waitcnt vmcnt(4)" ::: "memory"); // stage s landed (mine)
        } else {
            asm volatile("s_waitcnt vmcnt(0)" ::: "memory");
        }
        __builtin_amdgcn_s_barrier();          // everyone's stage s landed
        __builtin_amdgcn_sched_barrier(0);     // no LDS reads hoisted above

        const int n   = s * 64 + row;
        const int buf = s & 1;

        const float4 xa0 = *(const float4*)(xb0 + (size_t)n * CIN + ih * 4);
        const float4 xa1 = *(const float4*)(xb1 + (size_t)n * CIN + ih * 4);
        const float xs0[4] = {xa0.x, xa0.y, xa0.z, xa0.w};
        const float xs1[4] = {xa1.x, xa1.y, xa1.z, xa1.w};

        float a0[4] = {0.f, 0.f, 0.f, 0.f};
        float a1[4] = {0.f, 0.f, 0.f, 0.f};
        #pragma unroll
        for (int ii = 0; ii < 4; ++ii) {
            const int raw = row * 512 + (ih * 4 + ii) * 64 + oq * 16;
            const int sw  = raw ^ ((row & 7) << 4);
            const float4 wv = *(const float4*)(&w_lds[buf][sw]);
            const float wk[4] = {wv.x, wv.y, wv.z, wv.w};
            #pragma unroll
            for (int k = 0; k < 4; ++k) {
                a0[k] = fmaf(xs0[ii], wk[k], a0[k]);
                a1[k] = fmaf(xs1[ii], wk[k], a1[k]);
            }
        }
        // sum the two i-halves across partner lanes; both lanes end up with
        // full sums for both b's.
        #pragma unroll
        for (int k = 0; k < 4; ++k) {
            a0[k] += __shfl_xor(a0[k], 1);
            a1[k] += __shfl_xor(a1[k], 1);
        }
        // lane ih writes b_ih's o-quad (branchless element select, no
        // dynamic array indexing -> stays in registers)
        float s0 = ih ? a1[0] : a0[0];
        float s1 = ih ? a1[1] : a0[1];
        float s2 = ih ? a1[2] : a0[2];
        float s3 = ih ? a1[3] : a0[3];
        union { unsigned short us[4]; uint2 v; } pk;
        pk.us[0] = __bfloat16_as_ushort(__float2bfloat16(s0));
        pk.us[1] = __bfloat16_as_ushort(__float2bfloat16(s1));
        pk.us[2] = __bfloat16_as_ushort(__float2bfloat16(s2));
        pk.us[3] = __bfloat16_as_ushort(__float2bfloat16(s3));
        const int jj   = n >> 7;
        const int n127 = n & 127;
        uint4* slot = &u_lds[ih * (JPT * 256) + jj * 256 + n127 * 2 + (oq >> 1)];
        *(uint2*)((char*)slot + (oq & 1) * 8) = pk.v;

        asm volatile("s_waitcnt lgkmcnt(0)" ::: "memory"); // w reads + u writes done
        __builtin_amdgcn_s_barrier();          // buf[s&1] free for stage s+2
    }

    // ---- Phase 2: 3-iteration routing; waves 0-3 -> b0, waves 4-7 -> b1 ----
    const int bsel = t >> 8;
    const int tl   = t & 255;
    const int oh   = tl & 1;
    const uint4* up = u_lds + bsel * (JPT * 256);

    float bb[JPT];
    #pragma unroll
    for (int j = 0; j < JPT; ++j) bb[j] = 0.f;

    #pragma unroll
    for (int it = 0; it < 3; ++it) {
        float p8[8] = {0.f,0.f,0.f,0.f,0.f,0.f,0.f,0.f};
        float z = 0.f;
        if (it == 0) {
            #pragma unroll
            for (int j = 0; j < JPT; ++j) {
                float uf[8]; unpack8(up[j * 256 + tl], uf);
                #pragma unroll
                for (int k = 0; k < 8; ++k) p8[k] += uf[k];
            }
        } else {
            #pragma unroll
            for (int j = 0; j < JPT; ++j) {
                float e = __expf(bb[j] - 20.f);   // constant-shift softmax
                z += e;
                float uf[8]; unpack8(up[j * 256 + tl], uf);
                #pragma unroll
                for (int k = 0; k < 8; ++k) p8[k] = fmaf(e, uf[k], p8[k]);
            }
        }
        #pragma unroll
        for (int off = 2; off < 64; off <<= 1) {
            #pragma unroll
            for (int k = 0; k < 8; ++k) p8[k] += __shfl_xor(p8[k], off);
            if (it != 0) z += __shfl_xor(z, off);
        }
        if (lane < 2) {
            #pragma unroll
            for (int k = 0; k < 8; ++k) red[wave][oh * 8 + k] = p8[k];
            if (it != 0 && lane == 0) zred[wave] = z;
        }
        __syncthreads();

        if (t < 32) {   // t = bs*16 + o: combine the 4 waves of each b
            const int bs = t >> 4;
            const int o  = t & 15;
            float sv = red[bs * 4][o];
            #pragma unroll
            for (int wv = 1; wv < 4; ++wv) sv += red[bs * 4 + wv][o];
            float scale;
            if (it == 0) {
                scale = 1.f / (float)NCAPS;
            } else {
                float Z = zred[bs * 4];
                #pragma unroll
                for (int wv = 1; wv < 4; ++wv) Z += zred[bs * 4 + wv];
                scale = 1.f / Z;
            }
            sv *= scale;
            float v = sv * fabsf(sv) / (1.f + sv * sv);
            vsh[bs][o] = v;
            if (it == 2)
                out[((size_t)d * BATCH + b0 + bs) * COUT + o] = v;
        }
        __syncthreads();

        if (it < 2) {
            float vloc[8];
            #pragma unroll
            for (int k = 0; k < 8; ++k) vloc[k] = vsh[bsel][oh * 8 + k];
            #pragma unroll
            for (int j = 0; j < JPT; ++j) {
                float uf[8]; unpack8(up[j * 256 + tl], uf);
                float dv = 0.f;
                #pragma unroll
                for (int k = 0; k < 8; ++k) dv = fmaf(uf[k], vloc[k], dv);
                dv += __shfl_xor(dv, 1);   // add the other o-half
                bb[j] += dv;
            }
            __syncthreads();   // vsh/red reused next iteration
        }
    }
}

extern "C" void kernel_launch(void* const* d_in, const int* in_sizes, int n_in,
                              void* d_out, int out_size, void* d_ws, size_t ws_size,
                              hipStream_t stream) {
    const float* x = (const float*)d_in[0];
    const float* w = (const float*)d_in[1];
    float* out = (float*)d_out;
    (void)d_ws; (void)ws_size;

    fused_caps_kernel<<<DCAPS * (BATCH / 2), BNT, 0, stream>>>(x, w, out);
}

// Round 7
// 114.303 us; speedup vs baseline: 1.1703x; 1.1703x over previous
//
#include <hip/hip_runtime.h>
#include <hip/hip_bf16.h>
#include <math.h>

constexpr int NCAPS = 1152;
constexpr int CIN   = 8;
constexpr int COUT  = 16;
constexpr int BATCH = 128;
constexpr int DCAPS = 10;

// R7: R5's simple direct-load structure, widened to 4 b's per block.
//
// R5 (64 us) limiter: per-CU L1 fill of w -- 5 (d,b)-blocks/CU x 590 KB
// w[d] each ~ 3 MB/CU ~ 19 us at 64 B/cy, plus 755 MB L2 traffic (~22 us).
// R6's DMA+lockstep pipeline regressed (84 us): 1-deep prefetch can't hide
// DMA latency at 1 block/CU, and the stage swizzle had structural 4-way
// bank conflicts (rows stride 512 ≡ 0 mod 128).
//
// R7: keep R5's w access (lane pairs consume full 64-B lines, L1-friendly,
// zero asm) but amortize w[d] over 4 b's: 320 blocks x 512 thr; u for 4 b's
// lives in LDS (4 x 36.9 KB = 147.5 KB) -> 1 block/CU.
//   w L2 traffic: 755 -> 189 MB (~5.5 us at 34.5 TB/s)
//   per-CU L1 fill: ~3 MB -> ~0.92 MB (w 590K + x 147K + reuse)
// Bonus: 148 KB LDS makes occupancy LDS-bound, so the register allocator
// has no occupancy reason to clamp VGPRs (the R1-R4 spill fight dissolves;
// R6 evidence: 140 KB LDS -> 88 regs granted vs 64 at 512 B LDS).
//
// Phase 1: thread (h, oh, r): h = which b-pair, oh = o-half, r = row mod 128.
// Loads its oh-half of w row n once (16 float4, full 64-B lines per lane
// pair), x for its 2 b's, 128 FMA/j, packs 2 uint4 to u_lds. The two
// h-halves load identical w -> L1 broadcast on the same CU.
// Phase 2: 4 b's in parallel: 128 threads/b (2 waves), 18 half-rows/thread,
// same routing math as R5 (constant-shift softmax, pair-shuffle dv).
//
// Block->(d,bq) mapping groups same-d blocks onto the same XCD.

constexpr int BNT  = 512;
constexpr int JPT2 = 18;              // phase-2 half-rows per thread (128 thr/b)
constexpr int UST  = 9 * 256;         // uint4 slots per b

__device__ __forceinline__ void unpack8(const uint4 pv, float* f) {
    f[0] = __uint_as_float(pv.x << 16);
    f[1] = __uint_as_float(pv.x & 0xffff0000u);
    f[2] = __uint_as_float(pv.y << 16);
    f[3] = __uint_as_float(pv.y & 0xffff0000u);
    f[4] = __uint_as_float(pv.z << 16);
    f[5] = __uint_as_float(pv.z & 0xffff0000u);
    f[6] = __uint_as_float(pv.w << 16);
    f[7] = __uint_as_float(pv.w & 0xffff0000u);
}

__global__ __launch_bounds__(BNT) void fused_caps_kernel(
    const float* __restrict__ x,      // [128, 1152, 8]
    const float* __restrict__ w,      // [10, 1152, 8, 16]
    float* __restrict__ out)          // [10, 128, 16]
{
    __shared__ uint4 u_lds[4 * UST];  // 147456 B packed bf16 u for 4 b's
    __shared__ float red[8][COUT];    // per-wave partial s
    __shared__ float zred[8];         // per-wave exp-sum
    __shared__ float vsh[4][COUT];    // squashed v per b

    // ---- block -> (d, b-quad), XCD-grouped by d (bijective over 320) ----
    const int i = blockIdx.x;
    int d, bq;
    if (i < 256) { d = i & 7; bq = i >> 3; }
    else { const int j2 = i - 256; d = 8 + (j2 & 1); bq = j2 >> 1; }
    const int b0 = bq * 4;

    const int t    = threadIdx.x;
    const int wave = t >> 6;
    const int lane = t & 63;

    // ---- Phase 1: u for 4 b's into LDS. thread = (h, oh, r) ----
    const int h  = t >> 8;            // b-pair within quad
    const int tl = t & 255;
    const int oh = tl & 1;            // o-half
    const int r  = tl >> 1;           // 0..127

    const int bA = b0 + 2 * h;
    const float* xA = x + (size_t)bA * (NCAPS * CIN);
    const float* xB = xA + NCAPS * CIN;
    const float* wd = w + (size_t)d * ((size_t)NCAPS * CIN * COUT) + oh * 8;

    #pragma unroll
    for (int j = 0; j < 9; ++j) {
        const int n = j * 128 + r;
        const float4* xra = (const float4*)(xA + (size_t)n * CIN);
        const float4* xrb = (const float4*)(xB + (size_t)n * CIN);
        const float4 xa0 = xra[0], xa1 = xra[1];
        const float4 xb0v = xrb[0], xb1v = xrb[1];
        const float xsA[8] = {xa0.x, xa0.y, xa0.z, xa0.w,
                              xa1.x, xa1.y, xa1.z, xa1.w};
        const float xsB[8] = {xb0v.x, xb0v.y, xb0v.z, xb0v.w,
                              xb1v.x, xb1v.y, xb1v.z, xb1v.w};
        const float* wr = wd + (size_t)n * (CIN * COUT);
        float4 aA0 = {0.f,0.f,0.f,0.f}, aA1 = {0.f,0.f,0.f,0.f};
        float4 aB0 = {0.f,0.f,0.f,0.f}, aB1 = {0.f,0.f,0.f,0.f};
        #pragma unroll
        for (int ii = 0; ii < CIN; ++ii) {
            const float4 w0 = *(const float4*)(wr + ii * COUT);
            const float4 w1 = *(const float4*)(wr + ii * COUT + 4);
            aA0.x = fmaf(xsA[ii], w0.x, aA0.x);
            aA0.y = fmaf(xsA[ii], w0.y, aA0.y);
            aA0.z = fmaf(xsA[ii], w0.z, aA0.z);
            aA0.w = fmaf(xsA[ii], w0.w, aA0.w);
            aA1.x = fmaf(xsA[ii], w1.x, aA1.x);
            aA1.y = fmaf(xsA[ii], w1.y, aA1.y);
            aA1.z = fmaf(xsA[ii], w1.z, aA1.z);
            aA1.w = fmaf(xsA[ii], w1.w, aA1.w);
            aB0.x = fmaf(xsB[ii], w0.x, aB0.x);
            aB0.y = fmaf(xsB[ii], w0.y, aB0.y);
            aB0.z = fmaf(xsB[ii], w0.z, aB0.z);
            aB0.w = fmaf(xsB[ii], w0.w, aB0.w);
            aB1.x = fmaf(xsB[ii], w1.x, aB1.x);
            aB1.y = fmaf(xsB[ii], w1.y, aB1.y);
            aB1.z = fmaf(xsB[ii], w1.z, aB1.z);
            aB1.w = fmaf(xsB[ii], w1.w, aB1.w);
        }
        union { unsigned short us[8]; uint4 v; } pkA, pkB;
        pkA.us[0] = __bfloat16_as_ushort(__float2bfloat16(aA0.x));
        pkA.us[1] = __bfloat16_as_ushort(__float2bfloat16(aA0.y));
        pkA.us[2] = __bfloat16_as_ushort(__float2bfloat16(aA0.z));
        pkA.us[3] = __bfloat16_as_ushort(__float2bfloat16(aA0.w));
        pkA.us[4] = __bfloat16_as_ushort(__float2bfloat16(aA1.x));
        pkA.us[5] = __bfloat16_as_ushort(__float2bfloat16(aA1.y));
        pkA.us[6] = __bfloat16_as_ushort(__float2bfloat16(aA1.z));
        pkA.us[7] = __bfloat16_as_ushort(__float2bfloat16(aA1.w));
        pkB.us[0] = __bfloat16_as_ushort(__float2bfloat16(aB0.x));
        pkB.us[1] = __bfloat16_as_ushort(__float2bfloat16(aB0.y));
        pkB.us[2] = __bfloat16_as_ushort(__float2bfloat16(aB0.z));
        pkB.us[3] = __bfloat16_as_ushort(__float2bfloat16(aB0.w));
        pkB.us[4] = __bfloat16_as_ushort(__float2bfloat16(aB1.x));
        pkB.us[5] = __bfloat16_as_ushort(__float2bfloat16(aB1.y));
        pkB.us[6] = __bfloat16_as_ushort(__float2bfloat16(aB1.z));
        pkB.us[7] = __bfloat16_as_ushort(__float2bfloat16(aB1.w));
        u_lds[(2 * h)     * UST + j * 256 + tl] = pkA.v;
        u_lds[(2 * h + 1) * UST + j * 256 + tl] = pkB.v;
    }

    __syncthreads();   // u complete, cross-thread reads follow

    // ---- Phase 2: routing; 128 threads per b (2 waves/b) ----
    const int g  = t >> 7;            // b-group 0..3
    const int tg = t & 127;
    const uint4* up = u_lds + g * UST;

    float bb[JPT2];
    #pragma unroll
    for (int jj = 0; jj < JPT2; ++jj) bb[jj] = 0.f;

    #pragma unroll
    for (int it = 0; it < 3; ++it) {
        float p8[8] = {0.f,0.f,0.f,0.f,0.f,0.f,0.f,0.f};
        float z = 0.f;
        if (it == 0) {
            #pragma unroll
            for (int jj = 0; jj < JPT2; ++jj) {
                const int slot = (jj >> 1) * 256 + (jj & 1) * 128 + tg;
                float uf[8]; unpack8(up[slot], uf);
                #pragma unroll
                for (int k = 0; k < 8; ++k) p8[k] += uf[k];
            }
        } else {
            #pragma unroll
            for (int jj = 0; jj < JPT2; ++jj) {
                const int slot = (jj >> 1) * 256 + (jj & 1) * 128 + tg;
                float e = __expf(bb[jj] - 20.f);   // constant-shift softmax
                z += e;
                float uf[8]; unpack8(up[slot], uf);
                #pragma unroll
                for (int k = 0; k < 8; ++k) p8[k] = fmaf(e, uf[k], p8[k]);
            }
        }
        // reduce over lane bits 1..5; lanes 0/1 of each wave hold the wave
        // sums for their o-half; z on lane 0 counts each n exactly once.
        #pragma unroll
        for (int off = 2; off < 64; off <<= 1) {
            #pragma unroll
            for (int k = 0; k < 8; ++k) p8[k] += __shfl_xor(p8[k], off);
            if (it != 0) z += __shfl_xor(z, off);
        }
        if (lane < 2) {
            #pragma unroll
            for (int k = 0; k < 8; ++k) red[wave][(lane & 1) * 8 + k] = p8[k];
            if (it != 0 && lane == 0) zred[wave] = z;
        }
        __syncthreads();

        if (t < 64) {   // t = g2*16 + o: combine the 2 waves of each b
            const int g2 = t >> 4;
            const int o  = t & 15;
            float sv = red[2 * g2][o] + red[2 * g2 + 1][o];
            float scale;
            if (it == 0) {
                scale = 1.f / (float)NCAPS;
            } else {
                scale = 1.f / (zred[2 * g2] + zred[2 * g2 + 1]);
            }
            sv *= scale;
            float v = sv * fabsf(sv) / (1.f + sv * sv);
            vsh[g2][o] = v;
            if (it == 2)
                out[((size_t)d * BATCH + b0 + g2) * COUT + o] = v;
        }
        __syncthreads();

        if (it < 2) {
            const int oh2 = t & 1;
            float vloc[8];
            #pragma unroll
            for (int k = 0; k < 8; ++k) vloc[k] = vsh[g][oh2 * 8 + k];
            #pragma unroll
            for (int jj = 0; jj < JPT2; ++jj) {
                const int slot = (jj >> 1) * 256 + (jj & 1) * 128 + tg;
                float uf[8]; unpack8(up[slot], uf);
                float dv = 0.f;
                #pragma unroll
                for (int k = 0; k < 8; ++k) dv = fmaf(uf[k], vloc[k], dv);
                dv += __shfl_xor(dv, 1);   // add the other o-half
                bb[jj] += dv;
            }
            __syncthreads();   // vsh/red reused next iteration
        }
    }
}

extern "C" void kernel_launch(void* const* d_in, const int* in_sizes, int n_in,
                              void* d_out, int out_size, void* d_ws, size_t ws_size,
                              hipStream_t stream) {
    const float* x = (const float*)d_in[0];
    const float* w = (const float*)d_in[1];
    float* out = (float*)d_out;
    (void)d_ws; (void)ws_size;

    fused_caps_kernel<<<DCAPS * (BATCH / 4), BNT, 0, stream>>>(x, w, out);
}

// Round 8
// 100.113 us; speedup vs baseline: 1.3362x; 1.1417x over previous
//
#include <hip/hip_runtime.h>
#include <hip/hip_bf16.h>
#include <math.h>

constexpr int NCAPS = 1152;
constexpr int CIN   = 8;
constexpr int COUT  = 16;
constexpr int BATCH = 128;
constexpr int DCAPS = 10;

// R8: kill the phase-1 w gather via a pre-shuffled w copy (w5) in workspace.
//
// R5/R7 invariance (64 vs 62 us across 4x different w traffic and 2x
// occupancy) -> limiter is L1 ADDRESS throughput: each w load instruction
// was a 32-line stride-512 gather (~32 cy of TA pipe each); 46-104 K cy/CU
// of pure address processing. Fix:
//  - wshuf pre-kernel writes w5[((d*9+j)*8 + iiL*2 + p)][t] = the exact f4
//    lane t consumes -> phase-1 w loads are base + t*16B: 1 KB/instr,
//    16 fully-used lines, each line fetched once.
//  - i-dim split across lane pairs (h = lane bit 0): the two 256-thread
//    halves load DISJOINT planes (no duplicate loads); partial sums
//    combined with one __shfl_xor(.,1) per accumulator component.
// Per block: w 590 KB = 9.2 K cy L1 pipe (~3.8 us) overlapped with ~3 us
// FMA; 2 grid-rounds (320 blocks / 256 CUs) + phase 2 -> ~20-26 us kernel.
//
// Phase 2 (routing) is R7's, verbatim: 4 b's in parallel, 128 thr/b,
// constant-shift softmax, pair-shuffle dv. u layout in LDS unchanged:
// slot[gb*2304 + j*256 + r*2 + oh] = packed bf16 u[b0+gb][j*128+r][oh*8..+7].

constexpr int BNT  = 512;
constexpr int JPT2 = 18;              // phase-2 half-rows per thread (128 thr/b)
constexpr int UST  = 9 * 256;         // uint4 slots per b

__device__ __forceinline__ void unpack8(const uint4 pv, float* f) {
    f[0] = __uint_as_float(pv.x << 16);
    f[1] = __uint_as_float(pv.x & 0xffff0000u);
    f[2] = __uint_as_float(pv.y << 16);
    f[3] = __uint_as_float(pv.y & 0xffff0000u);
    f[4] = __uint_as_float(pv.z << 16);
    f[5] = __uint_as_float(pv.z & 0xffff0000u);
    f[6] = __uint_as_float(pv.w << 16);
    f[7] = __uint_as_float(pv.w & 0xffff0000u);
}

// ---- pre-shuffle: w5[blk][t], blk = (d*9+j)*8 + iiL*2 + p ----
// value = w[d][j*128 + (t>>2)][(t&1)*4 + iiL][((t>>1)&1)*8 + p*4 .. +3]
__global__ __launch_bounds__(256) void wshuf_kernel(
    const float* __restrict__ w, float4* __restrict__ w5)
{
    const int blk = blockIdx.x;       // 0..719
    const int d    = blk / 72;
    const int rem  = blk % 72;
    const int j    = rem >> 3;
    const int plane= rem & 7;
    const int iiL  = plane >> 1, p = plane & 1;
    const int tt   = threadIdx.x;
    #pragma unroll
    for (int half = 0; half < 2; ++half) {
        const int t  = half * 256 + tt;
        const int r  = t >> 2;
        const int oh = (t >> 1) & 1;
        const int h  = t & 1;
        const int ii = h * 4 + iiL;
        const int o0 = oh * 8 + p * 4;
        const float* src =
            w + ((size_t)((d * NCAPS + j * 128 + r) * CIN + ii)) * COUT + o0;
        w5[(size_t)blk * 512 + t] = *(const float4*)src;
    }
}

#define FMA8(XS, AL, AH)                                        \
    AL.x = fmaf(XS, wl.x, AL.x); AL.y = fmaf(XS, wl.y, AL.y);   \
    AL.z = fmaf(XS, wl.z, AL.z); AL.w = fmaf(XS, wl.w, AL.w);   \
    AH.x = fmaf(XS, wh.x, AH.x); AH.y = fmaf(XS, wh.y, AH.y);   \
    AH.z = fmaf(XS, wh.z, AH.z); AH.w = fmaf(XS, wh.w, AH.w);

#define COMB(A)                                                 \
    A.x += __shfl_xor(A.x, 1); A.y += __shfl_xor(A.y, 1);       \
    A.z += __shfl_xor(A.z, 1); A.w += __shfl_xor(A.w, 1);

__global__ __launch_bounds__(BNT) void fused_caps_kernel(
    const float*  __restrict__ x,     // [128, 1152, 8]
    const float4* __restrict__ w5,    // pre-shuffled w
    float*        __restrict__ out)   // [10, 128, 16]
{
    __shared__ uint4 u_lds[4 * UST];  // 147456 B packed bf16 u for 4 b's
    __shared__ float red[8][COUT];
    __shared__ float zred[8];
    __shared__ float vsh[4][COUT];

    // ---- block -> (d, b-quad), XCD-grouped by d (bijective over 320) ----
    const int i = blockIdx.x;
    int d, bq;
    if (i < 256) { d = i & 7; bq = i >> 3; }
    else { const int j2 = i - 256; d = 8 + (j2 & 1); bq = j2 >> 1; }
    const int b0 = bq * 4;

    const int t    = threadIdx.x;
    const int wave = t >> 6;
    const int lane = t & 63;

    // ---- Phase 1: thread = (h, oh, r); h = i-half (lane bit 0) ----
    const int h  = t & 1;
    const int oh = (t >> 1) & 1;
    const int r  = t >> 2;            // 0..127

    const float* x0 = x + (size_t)(b0 + 0) * (NCAPS * CIN) + h * 4;
    const float* x1 = x + (size_t)(b0 + 1) * (NCAPS * CIN) + h * 4;
    const float* x2 = x + (size_t)(b0 + 2) * (NCAPS * CIN) + h * 4;
    const float* x3 = x + (size_t)(b0 + 3) * (NCAPS * CIN) + h * 4;
    const float4* wb = w5 + (size_t)d * (9 * 8 * 512) + t;

    #pragma unroll
    for (int j = 0; j < 9; ++j) {
        const int n = j * 128 + r;
        // x: 4 f4 loads (lane quads share 32-B rows; rows consecutive)
        const float4 xv0 = *(const float4*)(x0 + (size_t)n * CIN);
        const float4 xv1 = *(const float4*)(x1 + (size_t)n * CIN);
        const float4 xv2 = *(const float4*)(x2 + (size_t)n * CIN);
        const float4 xv3 = *(const float4*)(x3 + (size_t)n * CIN);
        const float xs0[4] = {xv0.x, xv0.y, xv0.z, xv0.w};
        const float xs1[4] = {xv1.x, xv1.y, xv1.z, xv1.w};
        const float xs2[4] = {xv2.x, xv2.y, xv2.z, xv2.w};
        const float xs3[4] = {xv3.x, xv3.y, xv3.z, xv3.w};

        float4 a0l = {0,0,0,0}, a0h = {0,0,0,0};
        float4 a1l = {0,0,0,0}, a1h = {0,0,0,0};
        float4 a2l = {0,0,0,0}, a2h = {0,0,0,0};
        float4 a3l = {0,0,0,0}, a3h = {0,0,0,0};

        #pragma unroll
        for (int iiL = 0; iiL < 4; ++iiL) {
            // fully lane-contiguous: addr = plane_base + t*16B
            const float4 wl = wb[j * 4096 + iiL * 1024];        // p=0 (o0..3 of oh-half)
            const float4 wh = wb[j * 4096 + iiL * 1024 + 512];  // p=1 (o4..7 of oh-half)
            FMA8(xs0[iiL], a0l, a0h);
            FMA8(xs1[iiL], a1l, a1h);
            FMA8(xs2[iiL], a2l, a2h);
            FMA8(xs3[iiL], a3l, a3h);
        }
        // combine i-halves across lane pairs; both lanes get full sums
        COMB(a0l); COMB(a0h); COMB(a1l); COMB(a1h);
        COMB(a2l); COMB(a2h); COMB(a3l); COMB(a3h);

        // lane h packs b-slots {2h, 2h+1} (branchless f4 selects, static idx)
        const float4 AL0 = h ? a2l : a0l;
        const float4 AH0 = h ? a2h : a0h;
        const float4 AL1 = h ? a3l : a1l;
        const float4 AH1 = h ? a3h : a1h;

        union { unsigned short us[8]; uint4 v; } pk0, pk1;
        pk0.us[0] = __bfloat16_as_ushort(__float2bfloat16(AL0.x));
        pk0.us[1] = __bfloat16_as_ushort(__float2bfloat16(AL0.y));
        pk0.us[2] = __bfloat16_as_ushort(__float2bfloat16(AL0.z));
        pk0.us[3] = __bfloat16_as_ushort(__float2bfloat16(AL0.w));
        pk0.us[4] = __bfloat16_as_ushort(__float2bfloat16(AH0.x));
        pk0.us[5] = __bfloat16_as_ushort(__float2bfloat16(AH0.y));
        pk0.us[6] = __bfloat16_as_ushort(__float2bfloat16(AH0.z));
        pk0.us[7] = __bfloat16_as_ushort(__float2bfloat16(AH0.w));
        pk1.us[0] = __bfloat16_as_ushort(__float2bfloat16(AL1.x));
        pk1.us[1] = __bfloat16_as_ushort(__float2bfloat16(AL1.y));
        pk1.us[2] = __bfloat16_as_ushort(__float2bfloat16(AL1.z));
        pk1.us[3] = __bfloat16_as_ushort(__float2bfloat16(AL1.w));
        pk1.us[4] = __bfloat16_as_ushort(__float2bfloat16(AH1.x));
        pk1.us[5] = __bfloat16_as_ushort(__float2bfloat16(AH1.y));
        pk1.us[6] = __bfloat16_as_ushort(__float2bfloat16(AH1.z));
        pk1.us[7] = __bfloat16_as_ushort(__float2bfloat16(AH1.w));

        const int slot = j * 256 + r * 2 + oh;
        u_lds[(h * 2)     * UST + slot] = pk0.v;
        u_lds[(h * 2 + 1) * UST + slot] = pk1.v;
    }

    __syncthreads();   // u complete

    // ---- Phase 2: routing; 128 threads per b (2 waves/b) -- R7 verbatim ----
    const int g  = t >> 7;            // b-group 0..3
    const int tg = t & 127;
    const uint4* up = u_lds + g * UST;

    float bb[JPT2];
    #pragma unroll
    for (int jj = 0; jj < JPT2; ++jj) bb[jj] = 0.f;

    #pragma unroll
    for (int it = 0; it < 3; ++it) {
        float p8[8] = {0.f,0.f,0.f,0.f,0.f,0.f,0.f,0.f};
        float z = 0.f;
        if (it == 0) {
            #pragma unroll
            for (int jj = 0; jj < JPT2; ++jj) {
                const int slot = (jj >> 1) * 256 + (jj & 1) * 128 + tg;
                float uf[8]; unpack8(up[slot], uf);
                #pragma unroll
                for (int k = 0; k < 8; ++k) p8[k] += uf[k];
            }
        } else {
            #pragma unroll
            for (int jj = 0; jj < JPT2; ++jj) {
                const int slot = (jj >> 1) * 256 + (jj & 1) * 128 + tg;
                float e = __expf(bb[jj] - 20.f);   // constant-shift softmax
                z += e;
                float uf[8]; unpack8(up[slot], uf);
                #pragma unroll
                for (int k = 0; k < 8; ++k) p8[k] = fmaf(e, uf[k], p8[k]);
            }
        }
        #pragma unroll
        for (int off = 2; off < 64; off <<= 1) {
            #pragma unroll
            for (int k = 0; k < 8; ++k) p8[k] += __shfl_xor(p8[k], off);
            if (it != 0) z += __shfl_xor(z, off);
        }
        if (lane < 2) {
            #pragma unroll
            for (int k = 0; k < 8; ++k) red[wave][(lane & 1) * 8 + k] = p8[k];
            if (it != 0 && lane == 0) zred[wave] = z;
        }
        __syncthreads();

        if (t < 64) {   // t = g2*16 + o
            const int g2 = t >> 4;
            const int o  = t & 15;
            float sv = red[2 * g2][o] + red[2 * g2 + 1][o];
            float scale;
            if (it == 0) scale = 1.f / (float)NCAPS;
            else         scale = 1.f / (zred[2 * g2] + zred[2 * g2 + 1]);
            sv *= scale;
            float v = sv * fabsf(sv) / (1.f + sv * sv);
            vsh[g2][o] = v;
            if (it == 2)
                out[((size_t)d * BATCH + b0 + g2) * COUT + o] = v;
        }
        __syncthreads();

        if (it < 2) {
            const int oh2 = t & 1;
            float vloc[8];
            #pragma unroll
            for (int k = 0; k < 8; ++k) vloc[k] = vsh[g][oh2 * 8 + k];
            #pragma unroll
            for (int jj = 0; jj < JPT2; ++jj) {
                const int slot = (jj >> 1) * 256 + (jj & 1) * 128 + tg;
                float uf[8]; unpack8(up[slot], uf);
                float dv = 0.f;
                #pragma unroll
                for (int k = 0; k < 8; ++k) dv = fmaf(uf[k], vloc[k], dv);
                dv += __shfl_xor(dv, 1);   // add the other o-half
                bb[jj] += dv;
            }
            __syncthreads();
        }
    }
}

extern "C" void kernel_launch(void* const* d_in, const int* in_sizes, int n_in,
                              void* d_out, int out_size, void* d_ws, size_t ws_size,
                              hipStream_t stream) {
    const float* x = (const float*)d_in[0];
    const float* w = (const float*)d_in[1];
    float* out = (float*)d_out;
    float4* w5 = (float4*)d_ws;       // 720*512*16 B = 5.9 MB of the workspace

    wshuf_kernel<<<720, 256, 0, stream>>>(w, w5);
    fused_caps_kernel<<<DCAPS * (BATCH / 4), BNT, 0, stream>>>(x, w5, out);
}

// Round 9
// 97.092 us; speedup vs baseline: 1.3777x; 1.0311x over previous
//
#include <hip/hip_runtime.h>
#include <hip/hip_bf16.h>
#include <math.h>

constexpr int NCAPS = 1152;
constexpr int CIN   = 8;
constexpr int COUT  = 16;
constexpr int BATCH = 128;
constexpr int DCAPS = 10;

// R9: R8's pre-shuffled-w structure, re-tiled to 2 b's per block.
//
// R8 (fused ~41 us, just under the 42.5-us fill dispatches): gather fixed
// (w5 loads are base + t*16B, fully coalesced). Remaining cost is
// latency/imbalance: 320 blocks at 1 block/CU (148 KB LDS) -> 64 CUs run 2
// sequential blocks (2x critical path) and a lone 8-wave block exposes
// every barrier (Occupancy 13%).
//
// R9: 2 b's per block -> u = 73.8 KB LDS -> 2 blocks/CU, grid 640:
//  - tail 2.0 -> 1.25 rounds (640 blocks / 512 resident)
//  - two independent blocks per CU overlap barriers + memory latency
//    (4 waves/SIMD)
// Cost: per-CU w L1 fill rises to ~1.5 MB (each block streams the full
// 590-KB w[d]) but fully coalesced and overlapped by the co-resident block.
// w5 layout and phase-2 routing math are unchanged from R8 (verified).
//
// u layout per b: slot[j*256 + r*2 + oh] = packed bf16 u[b][j*128+r][oh*8..+7].

constexpr int BNT  = 512;
constexpr int UST  = 9 * 256;         // uint4 slots per b

__device__ __forceinline__ void unpack8(const uint4 pv, float* f) {
    f[0] = __uint_as_float(pv.x << 16);
    f[1] = __uint_as_float(pv.x & 0xffff0000u);
    f[2] = __uint_as_float(pv.y << 16);
    f[3] = __uint_as_float(pv.y & 0xffff0000u);
    f[4] = __uint_as_float(pv.z << 16);
    f[5] = __uint_as_float(pv.z & 0xffff0000u);
    f[6] = __uint_as_float(pv.w << 16);
    f[7] = __uint_as_float(pv.w & 0xffff0000u);
}

// ---- pre-shuffle: w5[blk][t], blk = (d*9+j)*8 + iiL*2 + p ----
// value = w[d][j*128 + (t>>2)][(t&1)*4 + iiL][((t>>1)&1)*8 + p*4 .. +3]
__global__ __launch_bounds__(256) void wshuf_kernel(
    const float* __restrict__ w, float4* __restrict__ w5)
{
    const int blk = blockIdx.x;       // 0..719
    const int d    = blk / 72;
    const int rem  = blk % 72;
    const int j    = rem >> 3;
    const int plane= rem & 7;
    const int iiL  = plane >> 1, p = plane & 1;
    const int tt   = threadIdx.x;
    #pragma unroll
    for (int half = 0; half < 2; ++half) {
        const int t  = half * 256 + tt;
        const int r  = t >> 2;
        const int oh = (t >> 1) & 1;
        const int h  = t & 1;
        const int ii = h * 4 + iiL;
        const int o0 = oh * 8 + p * 4;
        const float* src =
            w + ((size_t)((d * NCAPS + j * 128 + r) * CIN + ii)) * COUT + o0;
        w5[(size_t)blk * 512 + t] = *(const float4*)src;
    }
}

#define FMA8(XS, AL, AH)                                        \
    AL.x = fmaf(XS, wl.x, AL.x); AL.y = fmaf(XS, wl.y, AL.y);   \
    AL.z = fmaf(XS, wl.z, AL.z); AL.w = fmaf(XS, wl.w, AL.w);   \
    AH.x = fmaf(XS, wh.x, AH.x); AH.y = fmaf(XS, wh.y, AH.y);   \
    AH.z = fmaf(XS, wh.z, AH.z); AH.w = fmaf(XS, wh.w, AH.w);

#define COMB(A)                                                 \
    A.x += __shfl_xor(A.x, 1); A.y += __shfl_xor(A.y, 1);       \
    A.z += __shfl_xor(A.z, 1); A.w += __shfl_xor(A.w, 1);

__global__ __launch_bounds__(BNT) void fused_caps_kernel(
    const float*  __restrict__ x,     // [128, 1152, 8]
    const float4* __restrict__ w5,    // pre-shuffled w
    float*        __restrict__ out)   // [10, 128, 16]
{
    __shared__ uint4 u_lds[2 * UST];  // 73728 B packed bf16 u for 2 b's
    __shared__ float red[8][COUT];
    __shared__ float zred[8];
    __shared__ float vsh[2][COUT];

    // ---- block -> (d, b-pair), XCD-grouped by d (bijective over 640) ----
    const int i = blockIdx.x;
    int d, bp;
    if (i < 512) { d = i & 7; bp = i >> 3; }
    else { const int j2 = i - 512; d = 8 + (j2 & 1); bp = j2 >> 1; }
    const int b0 = bp * 2;

    const int t    = threadIdx.x;
    const int wave = t >> 6;
    const int lane = t & 63;

    // ---- Phase 1: thread = (h, oh, r); h = i-half (lane bit 0) ----
    const int h  = t & 1;
    const int oh = (t >> 1) & 1;
    const int r  = t >> 2;            // 0..127

    const float* x0 = x + (size_t)(b0 + 0) * (NCAPS * CIN) + h * 4;
    const float* x1 = x + (size_t)(b0 + 1) * (NCAPS * CIN) + h * 4;
    const float4* wb = w5 + (size_t)d * (9 * 8 * 512) + t;

    #pragma unroll
    for (int j = 0; j < 9; ++j) {
        const int n = j * 128 + r;
        const float4 xv0 = *(const float4*)(x0 + (size_t)n * CIN);
        const float4 xv1 = *(const float4*)(x1 + (size_t)n * CIN);
        const float xs0[4] = {xv0.x, xv0.y, xv0.z, xv0.w};
        const float xs1[4] = {xv1.x, xv1.y, xv1.z, xv1.w};

        float4 a0l = {0,0,0,0}, a0h = {0,0,0,0};
        float4 a1l = {0,0,0,0}, a1h = {0,0,0,0};

        #pragma unroll
        for (int iiL = 0; iiL < 4; ++iiL) {
            // fully lane-contiguous: addr = plane_base + t*16B
            const float4 wl = wb[j * 4096 + iiL * 1024];        // p=0
            const float4 wh = wb[j * 4096 + iiL * 1024 + 512];  // p=1
            FMA8(xs0[iiL], a0l, a0h);
            FMA8(xs1[iiL], a1l, a1h);
        }
        // combine i-halves across lane pairs; both lanes get full sums
        COMB(a0l); COMB(a0h); COMB(a1l); COMB(a1h);

        // lane h packs b0+h (branchless f4 selects, static indexing)
        const float4 AL = h ? a1l : a0l;
        const float4 AH = h ? a1h : a0h;

        union { unsigned short us[8]; uint4 v; } pk;
        pk.us[0] = __bfloat16_as_ushort(__float2bfloat16(AL.x));
        pk.us[1] = __bfloat16_as_ushort(__float2bfloat16(AL.y));
        pk.us[2] = __bfloat16_as_ushort(__float2bfloat16(AL.z));
        pk.us[3] = __bfloat16_as_ushort(__float2bfloat16(AL.w));
        pk.us[4] = __bfloat16_as_ushort(__float2bfloat16(AH.x));
        pk.us[5] = __bfloat16_as_ushort(__float2bfloat16(AH.y));
        pk.us[6] = __bfloat16_as_ushort(__float2bfloat16(AH.z));
        pk.us[7] = __bfloat16_as_ushort(__float2bfloat16(AH.w));

        u_lds[h * UST + j * 256 + r * 2 + oh] = pk.v;
    }

    __syncthreads();   // u complete

    // ---- Phase 2: routing; 256 threads per b (4 waves/b) ----
    const int g  = t >> 8;            // b-group 0..1
    const int tg = t & 255;
    const uint4* up = u_lds + g * UST;

    float bb[9];
    #pragma unroll
    for (int jj = 0; jj < 9; ++jj) bb[jj] = 0.f;

    #pragma unroll
    for (int it = 0; it < 3; ++it) {
        float p8[8] = {0.f,0.f,0.f,0.f,0.f,0.f,0.f,0.f};
        float z = 0.f;
        if (it == 0) {
            #pragma unroll
            for (int jj = 0; jj < 9; ++jj) {
                float uf[8]; unpack8(up[jj * 256 + tg], uf);
                #pragma unroll
                for (int k = 0; k < 8; ++k) p8[k] += uf[k];
            }
        } else {
            #pragma unroll
            for (int jj = 0; jj < 9; ++jj) {
                float e = __expf(bb[jj] - 20.f);   // constant-shift softmax
                z += e;
                float uf[8]; unpack8(up[jj * 256 + tg], uf);
                #pragma unroll
                for (int k = 0; k < 8; ++k) p8[k] = fmaf(e, uf[k], p8[k]);
            }
        }
        // reduce over lane bits 1..5; lanes 0/1 of each wave hold the wave
        // sums for their o-half; z on lane 0 counts each n exactly once.
        #pragma unroll
        for (int off = 2; off < 64; off <<= 1) {
            #pragma unroll
            for (int k = 0; k < 8; ++k) p8[k] += __shfl_xor(p8[k], off);
            if (it != 0) z += __shfl_xor(z, off);
        }
        if (lane < 2) {
            #pragma unroll
            for (int k = 0; k < 8; ++k) red[wave][(lane & 1) * 8 + k] = p8[k];
            if (it != 0 && lane == 0) zred[wave] = z;
        }
        __syncthreads();

        if (t < 32) {   // t = g2*16 + o: combine the 4 waves of each b
            const int g2 = t >> 4;
            const int o  = t & 15;
            float sv = red[g2 * 4][o];
            #pragma unroll
            for (int wv = 1; wv < 4; ++wv) sv += red[g2 * 4 + wv][o];
            float scale;
            if (it == 0) {
                scale = 1.f / (float)NCAPS;
            } else {
                float Z = zred[g2 * 4];
                #pragma unroll
                for (int wv = 1; wv < 4; ++wv) Z += zred[g2 * 4 + wv];
                scale = 1.f / Z;
            }
            sv *= scale;
            float v = sv * fabsf(sv) / (1.f + sv * sv);
            vsh[g2][o] = v;
            if (it == 2)
                out[((size_t)d * BATCH + b0 + g2) * COUT + o] = v;
        }
        __syncthreads();

        if (it < 2) {
            const int oh2 = tg & 1;
            float vloc[8];
            #pragma unroll
            for (int k = 0; k < 8; ++k) vloc[k] = vsh[g][oh2 * 8 + k];
            #pragma unroll
            for (int jj = 0; jj < 9; ++jj) {
                float uf[8]; unpack8(up[jj * 256 + tg], uf);
                float dv = 0.f;
                #pragma unroll
                for (int k = 0; k < 8; ++k) dv = fmaf(uf[k], vloc[k], dv);
                dv += __shfl_xor(dv, 1);   // add the other o-half
                bb[jj] += dv;
            }
            __syncthreads();   // vsh/red reused next iteration
        }
    }
}

extern "C" void kernel_launch(void* const* d_in, const int* in_sizes, int n_in,
                              void* d_out, int out_size, void* d_ws, size_t ws_size,
                              hipStream_t stream) {
    const float* x = (const float*)d_in[0];
    const float* w = (const float*)d_in[1];
    float* out = (float*)d_out;
    float4* w5 = (float4*)d_ws;       // 720*512*16 B = 5.9 MB of the workspace

    wshuf_kernel<<<720, 256, 0, stream>>>(w, w5);
    fused_caps_kernel<<<DCAPS * (BATCH / 2), BNT, 0, stream>>>(x, w5, out);
}